// Round 1
// baseline (170.108 us; speedup 1.0000x reference)
//
#include <hip/hip_runtime.h>

#define SGRID 14
#define L_COORD 5.0f
#define L_NOOBJ 0.5f

// ws layout: [0..3] double accumulators {reg, contain, noobj, cls}; offset 32: int fmt flag (1 = byte mask, 0 = int mask)

__global__ __launch_bounds__(256) void detect_init(const unsigned int* __restrict__ m,
                                                   int n_uints, double* __restrict__ acc,
                                                   int* __restrict__ fmt_flag) {
    __shared__ int found_s;
    if (threadIdx.x == 0) found_s = 0;
    __syncthreads();
    int found = 0;
    int base = threadIdx.x * 16;
    #pragma unroll
    for (int k = 0; k < 16; ++k) {
        int i = base + k;
        if (i < n_uints && m[i] > 1u) found = 1;
    }
    if (found) atomicOr(&found_s, 1);
    __syncthreads();
    if (threadIdx.x == 0) *fmt_flag = found_s;
    if (threadIdx.x < 4) acc[threadIdx.x] = 0.0;
}

__global__ __launch_bounds__(256) void yolo_main(const float* __restrict__ pred,
                                                 const float* __restrict__ tbox,
                                                 const float* __restrict__ tcls,
                                                 const void* __restrict__ maskp,
                                                 const int* __restrict__ fmt_flag,
                                                 double* __restrict__ acc,
                                                 int n_cells) {
    int cell = blockIdx.x * blockDim.x + threadIdx.x;
    float reg = 0.f, contain = 0.f, noobj = 0.f, cls = 0.f;
    if (cell < n_cells) {
        bool mask;
        if (*fmt_flag) mask = ((const unsigned char*)maskp)[cell] != 0;
        else           mask = ((const int*)maskp)[cell] != 0;

        const float* p = pred + (size_t)cell * 30;
        constexpr float invS = 1.0f / (float)SGRID;
        constexpr float sA = invS + 0.5f;

        if (mask) {
            // load all 30 floats (8B-aligned)
            float pv[30];
            #pragma unroll
            for (int k = 0; k < 15; ++k) {
                float2 v = ((const float2*)p)[k];
                pv[2 * k] = v.x; pv[2 * k + 1] = v.y;
            }
            float4 tb = ((const float4*)tbox)[cell];
            float tx1 = tb.x * invS - 0.5f * tb.z;
            float ty1 = tb.y * invS - 0.5f * tb.w;
            float tx2 = tb.z * sA;
            float ty2 = tb.w * sA;
            float ta = (tx2 - tx1) * (ty2 - ty1);

            float bx1[2], by1[2], bx2[2], by2[2], conf[2], iou[2];
            #pragma unroll
            for (int b = 0; b < 2; ++b) {
                float x = pv[b * 5 + 0], y = pv[b * 5 + 1];
                float w = pv[b * 5 + 2], h = pv[b * 5 + 3];
                conf[b] = pv[b * 5 + 4];
                bx1[b] = x * invS - 0.5f * w;
                by1[b] = y * invS - 0.5f * h;
                bx2[b] = w * sA;
                by2[b] = h * sA;
                float ltx = fmaxf(bx1[b], tx1), lty = fmaxf(by1[b], ty1);
                float rbx = fminf(bx2[b], tx2), rby = fminf(by2[b], ty2);
                float iw = fmaxf(rbx - ltx, 0.f), ih = fmaxf(rby - lty, 0.f);
                float inter = iw * ih;
                float a1 = (bx2[b] - bx1[b]) * (by2[b] - by1[b]);
                iou[b] = inter / (a1 + ta - inter);
            }
            int idx = (iou[1] > iou[0]) ? 1 : 0;       // jnp.argmax: first max wins on tie
            float biou = fmaxf(iou[0], iou[1]);

            float dx = tx1 - bx1[idx], dy = ty1 - by1[idx];
            float dxy = dx * dx + dy * dy;
            float sw = sqrtf(tx2) - sqrtf(bx2[idx]);
            float sh = sqrtf(ty2) - sqrtf(by2[idx]);
            float dwh = sw * sw + sh * sh;
            reg = L_COORD * (dxy + dwh);

            float dc = conf[idx] - biou;
            contain = dc * dc;

            const float4* tc = (const float4*)(tcls + (size_t)cell * 20);
            float c = 0.f;
            #pragma unroll
            for (int k = 0; k < 5; ++k) {
                float4 t = tc[k];
                float d0 = pv[10 + 4 * k + 0] - t.x;
                float d1 = pv[10 + 4 * k + 1] - t.y;
                float d2 = pv[10 + 4 * k + 2] - t.z;
                float d3 = pv[10 + 4 * k + 3] - t.w;
                c += d0 * d0 + d1 * d1 + d2 * d2 + d3 * d3;
            }
            cls = c;
        } else {
            float c0 = p[4], c1 = p[9];
            noobj = L_NOOBJ * (c0 * c0 + c1 * c1);
        }
    }

    // wave(64) reduce
    #pragma unroll
    for (int off = 32; off > 0; off >>= 1) {
        reg     += __shfl_down(reg, off, 64);
        contain += __shfl_down(contain, off, 64);
        noobj   += __shfl_down(noobj, off, 64);
        cls     += __shfl_down(cls, off, 64);
    }
    __shared__ float s[4][4];
    int wid = threadIdx.x >> 6, lane = threadIdx.x & 63;
    if (lane == 0) { s[wid][0] = reg; s[wid][1] = contain; s[wid][2] = noobj; s[wid][3] = cls; }
    __syncthreads();
    if (threadIdx.x == 0) {
        float r = 0.f, c = 0.f, n = 0.f, cl = 0.f;
        #pragma unroll
        for (int w = 0; w < 4; ++w) { r += s[w][0]; c += s[w][1]; n += s[w][2]; cl += s[w][3]; }
        atomicAdd(&acc[0], (double)r);
        atomicAdd(&acc[1], (double)c);
        atomicAdd(&acc[2], (double)n);
        atomicAdd(&acc[3], (double)cl);
    }
}

__global__ void finalize(const double* __restrict__ acc, float* __restrict__ out, float invN) {
    double reg = acc[0], contain = acc[1], noobj = acc[2], cls = acc[3];
    double total = reg + contain + noobj + cls;
    out[0] = (float)(total * (double)invN);
    out[1] = (float)(reg * (double)invN);
    out[2] = (float)(contain * (double)invN);
    out[3] = (float)(noobj * (double)invN);
    out[4] = (float)(cls * (double)invN);
}

extern "C" void kernel_launch(void* const* d_in, const int* in_sizes, int n_in,
                              void* d_out, int out_size, void* d_ws, size_t ws_size,
                              hipStream_t stream) {
    const float* pred = (const float*)d_in[0];
    const float* tbox = (const float*)d_in[1];
    const float* tcls = (const float*)d_in[2];
    const void*  mask = d_in[3];
    int n_cells = in_sizes[3];               // N * S * S
    int N = n_cells / (SGRID * SGRID);

    double* acc = (double*)d_ws;
    int* fmt = (int*)((char*)d_ws + 32);

    int n_uints = n_cells / 4;               // safe length in both mask layouts
    if (n_uints > 4096) n_uints = 4096;
    detect_init<<<1, 256, 0, stream>>>((const unsigned int*)mask, n_uints, acc, fmt);

    int blocks = (n_cells + 255) / 256;
    yolo_main<<<blocks, 256, 0, stream>>>(pred, tbox, tcls, mask, fmt, acc, n_cells);

    finalize<<<1, 1, 0, stream>>>(acc, (float*)d_out, 1.0f / (float)N);
}